// Round 1
// baseline (43822.235 us; speedup 1.0000x reference)
//
#include <hip/hip_runtime.h>
#include <hip/hip_bf16.h>

typedef __bf16 bf16_t;
typedef __bf16 bf16x8 __attribute__((ext_vector_type(8)));
typedef float  f32x4  __attribute__((ext_vector_type(4)));

#define S_LEN 1024
#define NBLK  64   // persistent blocks; each owns 16 r + 16 z + 16 n feature rows

__device__ inline f32x4 mfma16(bf16x8 a, bf16x8 b, f32x4 c) {
  return __builtin_amdgcn_mfma_f32_16x16x32_bf16(a, b, c, 0, 0, 0);
}
__device__ inline float fsigmoid(float x) {
  x = fmaxf(-30.f, fminf(30.f, x));
  return 1.f / (1.f + __expf(-x));
}
__device__ inline float ftanh(float x) {
  x = fmaxf(-15.f, fminf(15.f, x));
  float e = __expf(2.f * x);
  return (e - 1.f) / (e + 1.f);
}

// ---------------- cast input fp32 -> bf16 ----------------
__global__ void k_cast_x(const float* __restrict__ x, bf16_t* __restrict__ xb, int n8) {
  int i = blockIdx.x * blockDim.x + threadIdx.x;
  if (i >= n8) return;
  const float4* p = (const float4*)(x + (size_t)i * 8);
  float4 a = p[0], b = p[1];
  bf16x8 o;
  o[0]=(bf16_t)a.x; o[1]=(bf16_t)a.y; o[2]=(bf16_t)a.z; o[3]=(bf16_t)a.w;
  o[4]=(bf16_t)b.x; o[5]=(bf16_t)b.y; o[6]=(bf16_t)b.z; o[7]=(bf16_t)b.w;
  *(bf16x8*)(xb + (size_t)i * 8) = o;
}

// ---------------- pack weights (r,z,n concatenated rows), fold biases ----------------
__global__ void k_prep_w(const float* __restrict__ wihr, const float* __restrict__ whhr,
                         const float* __restrict__ wihz, const float* __restrict__ whhz,
                         const float* __restrict__ wihn, const float* __restrict__ whhn,
                         const float* __restrict__ bihr, const float* __restrict__ bhhr,
                         const float* __restrict__ bihz, const float* __restrict__ bhhz,
                         const float* __restrict__ bihn, const float* __restrict__ bhhn,
                         bf16_t* __restrict__ wih, bf16_t* __restrict__ whh,
                         float* __restrict__ bias) {
  int i = blockIdx.x * blockDim.x + threadIdx.x;
  const int M = 1024 * 1024;
  if (i < M) {
    wih[i]       = (bf16_t)wihr[i];
    wih[M + i]   = (bf16_t)wihz[i];
    wih[2*M + i] = (bf16_t)wihn[i];
    whh[i]       = (bf16_t)whhr[i];
    whh[M + i]   = (bf16_t)whhz[i];
    whh[2*M + i] = (bf16_t)whhn[i];
  }
  if (i < 1024) {
    bias[i]        = bihr[i] + bhhr[i];
    bias[1024 + i] = bihz[i] + bhhz[i];
    bias[2048 + i] = bihn[i] + bhhn[i];
  }
}

// ---------------- batched input-projection GEMM ----------------
// C[m][f] = sum_k Xb[m][k] * W[f][k] + bias[f];  M=65536, N=3072, K=1024
// f < 2048 -> bf16 xrz[m][f];  f >= 2048 -> fp32 xn staged into d_out[m][f-2048]
__global__ __launch_bounds__(256) void k_gemm(
    const bf16_t* __restrict__ A, const bf16_t* __restrict__ B,
    const float* __restrict__ bias,
    bf16_t* __restrict__ xrz, float* __restrict__ xn)
{
  __shared__ __align__(16) bf16_t As[128 * 32];
  __shared__ __align__(16) bf16_t Bs[128 * 32];
  const int tid  = threadIdx.x;
  const int lane = tid & 63;
  const int wid  = tid >> 6;
  const int wm   = wid & 1, wn = wid >> 1;
  const int quad = lane >> 4, l15 = lane & 15;
  const int m0 = blockIdx.x * 128;
  const int f0 = blockIdx.y * 128;

  const int r0 = tid >> 2,         o0 = (tid & 3) * 8;
  const int r1 = (tid + 256) >> 2, o1 = ((tid + 256) & 3) * 8;

  const bf16_t* Ag = A + (size_t)m0 * 1024;
  const bf16_t* Bg = B + (size_t)f0 * 1024;

  f32x4 acc[4][4] = {};

  bf16x8 pa0 = *(const bf16x8*)(Ag + r0 * 1024 + o0);
  bf16x8 pa1 = *(const bf16x8*)(Ag + r1 * 1024 + o1);
  bf16x8 pb0 = *(const bf16x8*)(Bg + r0 * 1024 + o0);
  bf16x8 pb1 = *(const bf16x8*)(Bg + r1 * 1024 + o1);

  for (int k0 = 0; k0 < 1024; k0 += 32) {
    __syncthreads();
    *(bf16x8*)&As[r0 * 32 + o0] = pa0;
    *(bf16x8*)&As[r1 * 32 + o1] = pa1;
    *(bf16x8*)&Bs[r0 * 32 + o0] = pb0;
    *(bf16x8*)&Bs[r1 * 32 + o1] = pb1;
    __syncthreads();
    if (k0 + 32 < 1024) {               // prefetch next K-slab under the MFMAs
      const bf16_t* Ag2 = Ag + k0 + 32;
      const bf16_t* Bg2 = Bg + k0 + 32;
      pa0 = *(const bf16x8*)(Ag2 + r0 * 1024 + o0);
      pa1 = *(const bf16x8*)(Ag2 + r1 * 1024 + o1);
      pb0 = *(const bf16x8*)(Bg2 + r0 * 1024 + o0);
      pb1 = *(const bf16x8*)(Bg2 + r1 * 1024 + o1);
    }
    bf16x8 af[4], bfr[4];
#pragma unroll
    for (int t = 0; t < 4; t++) {
      af[t]  = *(const bf16x8*)&As[(wm * 64 + t * 16 + l15) * 32 + quad * 8];
      bfr[t] = *(const bf16x8*)&Bs[(wn * 64 + t * 16 + l15) * 32 + quad * 8];
    }
#pragma unroll
    for (int mt = 0; mt < 4; mt++)
#pragma unroll
      for (int nt = 0; nt < 4; nt++)
        acc[mt][nt] = mfma16(af[mt], bfr[nt], acc[mt][nt]);
  }

  float bcol[4];
#pragma unroll
  for (int nt = 0; nt < 4; nt++) bcol[nt] = bias[f0 + wn * 64 + nt * 16 + l15];

  const bool is_n = (blockIdx.y >= 16);
#pragma unroll
  for (int mt = 0; mt < 4; mt++) {
#pragma unroll
    for (int nt = 0; nt < 4; nt++) {
#pragma unroll
      for (int j = 0; j < 4; j++) {
        int m = m0 + wm * 64 + mt * 16 + quad * 4 + j;   // C row = quad*4+reg (m89)
        int f = f0 + wn * 64 + nt * 16 + l15;            // C col = lane&15
        float v = acc[mt][nt][j] + bcol[nt];
        if (!is_n) xrz[(size_t)m * 2048 + f] = (bf16_t)v;
        else       xn[(size_t)m * 1024 + (f - 2048)] = v;
      }
    }
  }
}

// ---------------- flag init (ws is 0xAA-poisoned; barrier needs zeros) ----------------
__global__ void k_zero_flags(unsigned* f) { f[threadIdx.x] = 0; }

// Monotone-counter grid barrier: each block publishes step id, wave 0 polls all 64
// flags (one per lane) with >= so a missed exact value can't deadlock. Device-scope
// fences make rh/h stores visible across XCDs (per-XCD L2 non-coherent).
__device__ inline void gridbar(unsigned* flags, int bid, unsigned p) {
  __threadfence();          // every thread drains its own stores (vmcnt is per-wave)
  __syncthreads();
  if (threadIdx.x == 0)
    __hip_atomic_store(&flags[bid], p, __ATOMIC_RELEASE, __HIP_MEMORY_SCOPE_AGENT);
  if (threadIdx.x < NBLK) {
    while (__hip_atomic_load(&flags[threadIdx.x], __ATOMIC_RELAXED,
                             __HIP_MEMORY_SCOPE_AGENT) < p)
      __builtin_amdgcn_s_sleep(1);
  }
  __syncthreads();
  __threadfence();          // acquire: invalidate L1 so cross-block rh/h reads are fresh
}

// ---------------- persistent recurrent kernel ----------------
// Block bid owns feature columns [bid*16, bid*16+16) of r, z, n. W_hh rows LDS-resident.
// Wave w handles batches [16w, 16w+16). h kept fp32 (hf) + bf16 MFMA copy (hb).
__global__ __launch_bounds__(256) void k_gru(
    const bf16_t* __restrict__ xrz,  // [65536][2048] bf16 (bias folded)
    const bf16_t* __restrict__ whh,  // [3072][1024] bf16 (r,z,n rows)
    float* __restrict__ out,         // [S*64*1024] holds xn, overwritten with h; +[64*1024] h_n
    bf16_t* __restrict__ hb, float* __restrict__ hf,
    bf16_t* __restrict__ rh, unsigned* __restrict__ flags)
{
  __shared__ __align__(16) bf16_t wl[48 * 1032];   // 48 rows, +8 bf16 pad (99 KB)
  const int tid  = threadIdx.x;
  const int bid  = blockIdx.x;
  const int lane = tid & 63;
  const int wid  = tid >> 6;
  const int quad = lane >> 4, l15 = lane & 15;

  // stage this block's 48 W_hh rows into LDS
  for (int i = tid; i < 48 * 128; i += 256) {
    int row = i >> 7;            // 0..47 (0-15 r, 16-31 z, 32-47 n)
    int c   = (i & 127) * 8;
    int gr  = (row >> 4) * 1024 + bid * 16 + (row & 15);
    *(bf16x8*)&wl[row * 1032 + c] = *(const bf16x8*)&whh[(size_t)gr * 1024 + c];
  }
  // zero h (block-private columns)
  for (int i = tid; i < 64 * 16; i += 256) {
    int b = i >> 4, f = bid * 16 + (i & 15);
    hf[b * 1024 + f] = 0.f;
    hb[b * 1024 + f] = (bf16_t)0.f;
  }
  gridbar(flags, bid, 1);

  const int abase = (wid * 16 + l15) * 1024 + quad * 8;  // A-frag: m=lane&15 (m120)
  const int fg = bid * 16 + l15;                         // this lane's feature column
  unsigned p = 2;

  for (int t = 0; t < S_LEN; t++) {
    // ---- phase A: r,z GEMVs + rh ----
    f32x4 ar = {}, az = {};
    const bf16_t* hrow = hb + abase;
#pragma unroll 4
    for (int kk = 0; kk < 32; kk++) {
      bf16x8 a  = *(const bf16x8*)(hrow + kk * 32);
      bf16x8 br = *(const bf16x8*)&wl[l15 * 1032 + kk * 32 + quad * 8];
      bf16x8 bz = *(const bf16x8*)&wl[(16 + l15) * 1032 + kk * 32 + quad * 8];
      ar = mfma16(a, br, ar);
      az = mfma16(a, bz, az);
    }
    float zreg[4], hold[4];
    const int mrow = t * 64;
#pragma unroll
    for (int j = 0; j < 4; j++) {
      int b = wid * 16 + quad * 4 + j;                   // C row = quad*4+reg
      float xr = (float)xrz[(size_t)(mrow + b) * 2048 + fg];
      float xz = (float)xrz[(size_t)(mrow + b) * 2048 + 1024 + fg];
      float rv = fsigmoid(xr + ar[j]);
      float zv = fsigmoid(xz + az[j]);
      float hv = hf[b * 1024 + fg];
      zreg[j] = zv; hold[j] = hv;
      rh[b * 1024 + fg] = (bf16_t)(rv * hv);
    }
    gridbar(flags, bid, p); p++;

    // ---- phase B: n GEMV + state update ----
    f32x4 an = {};
    const bf16_t* rrow = rh + abase;
#pragma unroll 4
    for (int kk = 0; kk < 32; kk++) {
      bf16x8 a  = *(const bf16x8*)(rrow + kk * 32);
      bf16x8 bn = *(const bf16x8*)&wl[(32 + l15) * 1032 + kk * 32 + quad * 8];
      an = mfma16(a, bn, an);
    }
#pragma unroll
    for (int j = 0; j < 4; j++) {
      int b = wid * 16 + quad * 4 + j;
      size_t oix = (size_t)(mrow + b) * 1024 + fg;
      float xnv = out[oix];                              // staged xn (read before write)
      float nv  = ftanh(xnv + an[j]);
      float hv  = (1.f - zreg[j]) * nv + zreg[j] * hold[j];
      out[oix] = hv;
      hf[b * 1024 + fg] = hv;
      hb[b * 1024 + fg] = (bf16_t)hv;
      if (t == S_LEN - 1) out[(size_t)S_LEN * 64 * 1024 + b * 1024 + fg] = hv;
    }
    gridbar(flags, bid, p); p++;
  }
}

extern "C" void kernel_launch(void* const* d_in, const int* in_sizes, int n_in,
                              void* d_out, int out_size, void* d_ws, size_t ws_size,
                              hipStream_t stream) {
  const float* x    = (const float*)d_in[0];
  const float* wihr = (const float*)d_in[1];
  const float* whhr = (const float*)d_in[2];
  const float* wihz = (const float*)d_in[3];
  const float* whhz = (const float*)d_in[4];
  const float* wihn = (const float*)d_in[5];
  const float* whhn = (const float*)d_in[6];
  const float* bihr = (const float*)d_in[7];
  const float* bhhr = (const float*)d_in[8];
  const float* bihz = (const float*)d_in[9];
  const float* bhhz = (const float*)d_in[10];
  const float* bihn = (const float*)d_in[11];
  const float* bhhn = (const float*)d_in[12];
  float* out = (float*)d_out;

  // ws layout (≈396.5 MiB)
  char* w = (char*)d_ws;
  bf16_t*  Xb    = (bf16_t*)(w);                    // 134,217,728 B
  bf16_t*  xrz   = (bf16_t*)(w + 134217728);        // 268,435,456 B
  bf16_t*  wih   = (bf16_t*)(w + 402653184);        //   6,291,456 B
  bf16_t*  whh   = (bf16_t*)(w + 408944640);        //   6,291,456 B
  float*   bias  = (float*) (w + 415236096);        //      12,288 B
  float*   hf    = (float*) (w + 415248384);        //     262,144 B
  bf16_t*  hb    = (bf16_t*)(w + 415510528);        //     131,072 B
  bf16_t*  rh    = (bf16_t*)(w + 415641600);        //     131,072 B
  unsigned* flags = (unsigned*)(w + 415772672);     //         256 B

  k_cast_x<<<dim3(8388608 / 256), dim3(256), 0, stream>>>(x, Xb, 8388608);
  k_prep_w<<<dim3(1048576 / 256), dim3(256), 0, stream>>>(
      wihr, whhr, wihz, whhz, wihn, whhn,
      bihr, bhhr, bihz, bhhz, bihn, bhhn, wih, whh, bias);
  k_gemm<<<dim3(512, 24), dim3(256), 0, stream>>>(Xb, wih, bias, xrz, out);
  k_zero_flags<<<dim3(1), dim3(64), 0, stream>>>(flags);
  // 64 blocks on 256 CUs: all co-resident on dispatch (plain launch; custom barrier
  // uses monotone counters so a missed value cannot deadlock).
  k_gru<<<dim3(NBLK), dim3(256), 0, stream>>>(xrz, whh, out, hb, hf, rh, flags);
}